// Round 1
// baseline (648.053 us; speedup 1.0000x reference)
//
#include <hip/hip_runtime.h>

#define NN 50000
#define NE 800000
#define ET (NE + NN)          // edges + self loops
#define NEG_SLOPE 0.2f

__device__ __forceinline__ unsigned enc(float f) {
    unsigned u = __float_as_uint(f);
    return (u & 0x80000000u) ? ~u : (u | 0x80000000u);
}
__device__ __forceinline__ float dec(unsigned u) {
    return __uint_as_float((u & 0x80000000u) ? (u & 0x7FFFFFFFu) : ~u);
}
__device__ __forceinline__ float lrelu(float v) { return v > 0.f ? v : NEG_SLOPE * v; }

// ---- layer 1 GEMM: h1 = x @ W1 ([N,128]x[128,64]); fused a_s1/a_d1 (8 heads x 8 ch)
__global__ __launch_bounds__(256) void gemm1(const float* __restrict__ x,
                                             const float* __restrict__ W1,
                                             const float* __restrict__ att_s,
                                             const float* __restrict__ att_d,
                                             float* __restrict__ h1,
                                             float* __restrict__ a_s,
                                             float* __restrict__ a_d) {
    __shared__ float xs[4][128];
    int lane = threadIdx.x & 63;
    int row  = threadIdx.x >> 6;
    int n    = blockIdx.x * 4 + row;           // 50000 = 12500*4, exact
    xs[row][lane]      = x[n * 128 + lane];
    xs[row][lane + 64] = x[n * 128 + lane + 64];
    __syncthreads();
    float acc = 0.f;
#pragma unroll 8
    for (int k = 0; k < 128; ++k) acc += xs[row][k] * W1[k * 64 + lane];
    h1[n * 64 + lane] = acc;
    // head h = lane>>3, ch c = lane&7 ; att[h*8+c] == att[lane]
    float ps = acc * att_s[lane];
    float pd = acc * att_d[lane];
#pragma unroll
    for (int m = 1; m < 8; m <<= 1) { ps += __shfl_xor(ps, m, 64); pd += __shfl_xor(pd, m, 64); }
    if ((lane & 7) == 0) { int h = lane >> 3; a_s[n * 8 + h] = ps; a_d[n * 8 + h] = pd; }
}

// ---- layer 2 GEMM: h2 = xh @ W2 ([N,64]x[64,64]); fused a_s2/a_d2 (1 head x 64 ch)
__global__ __launch_bounds__(256) void gemm2(const float* __restrict__ xh,
                                             const float* __restrict__ W2,
                                             const float* __restrict__ att_s,
                                             const float* __restrict__ att_d,
                                             float* __restrict__ h2,
                                             float* __restrict__ a_s2,
                                             float* __restrict__ a_d2) {
    __shared__ float xs[4][64];
    int lane = threadIdx.x & 63;
    int row  = threadIdx.x >> 6;
    int n    = blockIdx.x * 4 + row;
    xs[row][lane] = xh[n * 64 + lane];
    __syncthreads();
    float acc = 0.f;
#pragma unroll 8
    for (int k = 0; k < 64; ++k) acc += xs[row][k] * W2[k * 64 + lane];
    h2[n * 64 + lane] = acc;
    float ps = acc * att_s[lane];
    float pd = acc * att_d[lane];
#pragma unroll
    for (int m = 1; m < 64; m <<= 1) { ps += __shfl_xor(ps, m, 64); pd += __shfl_xor(pd, m, 64); }
    if (lane == 0) { a_s2[n] = ps; a_d2[n] = pd; }
}

// ---- layer 1 edge passes (8 heads)
__global__ void emax1(const int* __restrict__ ei, const float* __restrict__ a_s,
                      const float* __restrict__ a_d, unsigned* __restrict__ m1) {
    int tid = blockIdx.x * blockDim.x + threadIdx.x;
    if (tid >= ET * 8) return;
    int e = tid >> 3, h = tid & 7;
    int s = e < NE ? ei[e] : e - NE;
    int d = e < NE ? ei[NE + e] : e - NE;
    float v = lrelu(a_s[s * 8 + h] + a_d[d * 8 + h]);
    atomicMax(&m1[d * 8 + h], enc(v));
}

__global__ void esum1(const int* __restrict__ ei, const float* __restrict__ a_s,
                      const float* __restrict__ a_d, const unsigned* __restrict__ m1,
                      float* __restrict__ s1) {
    int tid = blockIdx.x * blockDim.x + threadIdx.x;
    if (tid >= ET * 8) return;
    int e = tid >> 3, h = tid & 7;
    int s = e < NE ? ei[e] : e - NE;
    int d = e < NE ? ei[NE + e] : e - NE;
    float v = lrelu(a_s[s * 8 + h] + a_d[d * 8 + h]);
    atomicAdd(&s1[d * 8 + h], __expf(v - dec(m1[d * 8 + h])));
}

__global__ void escat1(const int* __restrict__ ei, const float* __restrict__ a_s,
                       const float* __restrict__ a_d, const unsigned* __restrict__ m1,
                       const float* __restrict__ s1, const float* __restrict__ h1,
                       float* __restrict__ out1) {
    int tid = blockIdx.x * blockDim.x + threadIdx.x;
    if (tid >= ET * 64) return;
    int e = tid >> 6, j = tid & 63, h = j >> 3;
    int s = e < NE ? ei[e] : e - NE;
    int d = e < NE ? ei[NE + e] : e - NE;
    float v = lrelu(a_s[s * 8 + h] + a_d[d * 8 + h]);
    float alpha = __expf(v - dec(m1[d * 8 + h])) / (s1[d * 8 + h] + 1e-16f);
    atomicAdd(&out1[d * 64 + j], h1[s * 64 + j] * alpha);
}

// ---- elementwise: xh = elu(out1 + b1)  (in place)
__global__ void post1(float* __restrict__ xh, const float* __restrict__ b1) {
    int tid = blockIdx.x * blockDim.x + threadIdx.x;
    if (tid >= NN * 64) return;
    float v = xh[tid] + b1[tid & 63];
    xh[tid] = v > 0.f ? v : expm1f(v);
}

// ---- layer 2 edge passes (1 head, 64 ch)
__global__ void emax2(const int* __restrict__ ei, const float* __restrict__ a_s,
                      const float* __restrict__ a_d, unsigned* __restrict__ m2) {
    int tid = blockIdx.x * blockDim.x + threadIdx.x;
    if (tid >= ET) return;
    int e = tid;
    int s = e < NE ? ei[e] : e - NE;
    int d = e < NE ? ei[NE + e] : e - NE;
    float v = lrelu(a_s[s] + a_d[d]);
    atomicMax(&m2[d], enc(v));
}

__global__ void esum2(const int* __restrict__ ei, const float* __restrict__ a_s,
                      const float* __restrict__ a_d, const unsigned* __restrict__ m2,
                      float* __restrict__ s2) {
    int tid = blockIdx.x * blockDim.x + threadIdx.x;
    if (tid >= ET) return;
    int e = tid;
    int s = e < NE ? ei[e] : e - NE;
    int d = e < NE ? ei[NE + e] : e - NE;
    float v = lrelu(a_s[s] + a_d[d]);
    atomicAdd(&s2[d], __expf(v - dec(m2[d])));
}

__global__ void escat2(const int* __restrict__ ei, const float* __restrict__ a_s,
                       const float* __restrict__ a_d, const unsigned* __restrict__ m2,
                       const float* __restrict__ s2, const float* __restrict__ h2,
                       float* __restrict__ out2) {
    int tid = blockIdx.x * blockDim.x + threadIdx.x;
    if (tid >= ET * 64) return;
    int e = tid >> 6, j = tid & 63;
    int s = e < NE ? ei[e] : e - NE;
    int d = e < NE ? ei[NE + e] : e - NE;
    float v = lrelu(a_s[s] + a_d[d]);
    float alpha = __expf(v - dec(m2[d])) / (s2[d] + 1e-16f);
    atomicAdd(&out2[d * 64 + j], h2[s * 64 + j] * alpha);
}

// ---- final: out = out2 + b2
__global__ void finalk(const float* __restrict__ out2, const float* __restrict__ b2,
                       float* __restrict__ out) {
    int tid = blockIdx.x * blockDim.x + threadIdx.x;
    if (tid >= NN * 64) return;
    out[tid] = out2[tid] + b2[tid & 63];
}

extern "C" void kernel_launch(void* const* d_in, const int* in_sizes, int n_in,
                              void* d_out, int out_size, void* d_ws, size_t ws_size,
                              hipStream_t stream) {
    const float* x     = (const float*)d_in[0];
    const int*   ei    = (const int*)d_in[1];
    const float* W1    = (const float*)d_in[2];
    const float* as1   = (const float*)d_in[3];
    const float* ad1   = (const float*)d_in[4];
    const float* b1    = (const float*)d_in[5];
    const float* W2    = (const float*)d_in[6];
    const float* as2   = (const float*)d_in[7];
    const float* ad2   = (const float*)d_in[8];
    const float* b2    = (const float*)d_in[9];
    float* out = (float*)d_out;

    float* ws = (float*)d_ws;
    float*    h1   = ws;                              // 3,200,000 (reused as out2 acc)
    float*    h2   = h1 + 3200000;                    // 3,200,000
    float*    a_s1 = h2 + 3200000;                    // 400,000
    float*    a_d1 = a_s1 + 400000;                   // 400,000
    float*    a_s2 = a_d1 + 400000;                   // 50,000
    float*    a_d2 = a_s2 + 50000;                    // 50,000
    // ---- zero-init region (single memset): xh/out1, m1, s1, m2, s2
    float*    xh   = a_d2 + 50000;                    // 3,200,000
    unsigned* m1   = (unsigned*)(xh + 3200000);       // 400,000
    float*    s1   = (float*)(m1 + 400000);           // 400,000
    unsigned* m2   = (unsigned*)(s1 + 400000);        // 50,000
    float*    s2   = (float*)(m2 + 50000);            // 50,000

    hipMemsetAsync(xh, 0, (size_t)4100000 * 4, stream);

    gemm1<<<12500, 256, 0, stream>>>(x, W1, as1, ad1, h1, a_s1, a_d1);
    emax1<<<(ET * 8 + 255) / 256, 256, 0, stream>>>(ei, a_s1, a_d1, m1);
    esum1<<<(ET * 8 + 255) / 256, 256, 0, stream>>>(ei, a_s1, a_d1, m1, s1);
    escat1<<<(ET * 64 + 255) / 256, 256, 0, stream>>>(ei, a_s1, a_d1, m1, s1, h1, xh);
    post1<<<(NN * 64 + 255) / 256, 256, 0, stream>>>(xh, b1);

    // h1 no longer needed -> reuse as out2 accumulator
    hipMemsetAsync(h1, 0, (size_t)3200000 * 4, stream);

    gemm2<<<12500, 256, 0, stream>>>(xh, W2, as2, ad2, h2, a_s2, a_d2);
    emax2<<<(ET + 255) / 256, 256, 0, stream>>>(ei, a_s2, a_d2, m2);
    esum2<<<(ET + 255) / 256, 256, 0, stream>>>(ei, a_s2, a_d2, m2, s2);
    escat2<<<(ET * 64 + 255) / 256, 256, 0, stream>>>(ei, a_s2, a_d2, m2, s2, h2, h1);
    finalk<<<(NN * 64 + 255) / 256, 256, 0, stream>>>(h1, b2, out);
}

// Round 2
// 386.808 us; speedup vs baseline: 1.6754x; 1.6754x over previous
//
#include <hip/hip_runtime.h>

#define NN 50000
#define NE 800000
#define NEG_SLOPE 0.2f

__device__ __forceinline__ float lrelu(float v) { return v > 0.f ? v : NEG_SLOPE * v; }

// ============ CSR build (dst-sorted) ============
__global__ void hist(const int* __restrict__ ei, int* __restrict__ deg) {
    int e = blockIdx.x * blockDim.x + threadIdx.x;
    if (e < NE) atomicAdd(&deg[ei[NE + e]], 1);
}

__global__ __launch_bounds__(256) void scan1(const int* __restrict__ deg,
                                             int* __restrict__ offs, int* __restrict__ bsum) {
    __shared__ int tmp[256];
    int i = blockIdx.x * 256 + threadIdx.x;
    int v = (i < NN) ? deg[i] : 0;
    tmp[threadIdx.x] = v;
    __syncthreads();
    for (int o = 1; o < 256; o <<= 1) {
        int t = (threadIdx.x >= o) ? tmp[threadIdx.x - o] : 0;
        __syncthreads();
        tmp[threadIdx.x] += t;
        __syncthreads();
    }
    if (i < NN) offs[i] = tmp[threadIdx.x] - v;          // exclusive, block-local
    if (threadIdx.x == 255) bsum[blockIdx.x] = tmp[255]; // block total
}

__global__ __launch_bounds__(256) void scan2(int* __restrict__ bsum) {
    __shared__ int tmp[256];
    int v = bsum[threadIdx.x];
    tmp[threadIdx.x] = v;
    __syncthreads();
    for (int o = 1; o < 256; o <<= 1) {
        int t = (threadIdx.x >= o) ? tmp[threadIdx.x - o] : 0;
        __syncthreads();
        tmp[threadIdx.x] += t;
        __syncthreads();
    }
    bsum[threadIdx.x] = tmp[threadIdx.x] - v;            // exclusive block offsets
}

__global__ void scan3(int* __restrict__ offs, const int* __restrict__ bsum,
                      int* __restrict__ cursor) {
    int i = blockIdx.x * blockDim.x + threadIdx.x;
    if (i < NN) { int o = offs[i] + bsum[i >> 8]; offs[i] = o; cursor[i] = o; }
}

__global__ void scatter(const int* __restrict__ ei, int* __restrict__ cursor,
                        int* __restrict__ srclist) {
    int e = blockIdx.x * blockDim.x + threadIdx.x;
    if (e < NE) {
        int d = ei[NE + e];
        int pos = atomicAdd(&cursor[d], 1);
        srclist[pos] = ei[e];
    }
}

// ============ GEMMs with fused attention-logit epilogues ============
__global__ __launch_bounds__(256) void gemm1(const float* __restrict__ x,
                                             const float* __restrict__ W1,
                                             const float* __restrict__ att_s,
                                             const float* __restrict__ att_d,
                                             float* __restrict__ h1,
                                             float* __restrict__ a_s,
                                             float* __restrict__ a_d) {
    __shared__ float xs[4][128];
    int lane = threadIdx.x & 63;
    int row  = threadIdx.x >> 6;
    int n    = blockIdx.x * 4 + row;
    xs[row][lane]      = x[n * 128 + lane];
    xs[row][lane + 64] = x[n * 128 + lane + 64];
    __syncthreads();
    float acc = 0.f;
#pragma unroll 8
    for (int k = 0; k < 128; ++k) acc += xs[row][k] * W1[k * 64 + lane];
    h1[n * 64 + lane] = acc;
    float ps = acc * att_s[lane];
    float pd = acc * att_d[lane];
#pragma unroll
    for (int m = 1; m < 8; m <<= 1) { ps += __shfl_xor(ps, m, 64); pd += __shfl_xor(pd, m, 64); }
    if ((lane & 7) == 0) { int h = lane >> 3; a_s[n * 8 + h] = ps; a_d[n * 8 + h] = pd; }
}

__global__ __launch_bounds__(256) void gemm2(const float* __restrict__ xh,
                                             const float* __restrict__ W2,
                                             const float* __restrict__ att_s,
                                             const float* __restrict__ att_d,
                                             float* __restrict__ h2,
                                             float* __restrict__ a_s2,
                                             float* __restrict__ a_d2) {
    __shared__ float xs[4][64];
    int lane = threadIdx.x & 63;
    int row  = threadIdx.x >> 6;
    int n    = blockIdx.x * 4 + row;
    xs[row][lane] = xh[n * 64 + lane];
    __syncthreads();
    float acc = 0.f;
#pragma unroll 8
    for (int k = 0; k < 64; ++k) acc += xs[row][k] * W2[k * 64 + lane];
    h2[n * 64 + lane] = acc;
    float ps = acc * att_s[lane];
    float pd = acc * att_d[lane];
#pragma unroll
    for (int m = 1; m < 64; m <<= 1) { ps += __shfl_xor(ps, m, 64); pd += __shfl_xor(pd, m, 64); }
    if (lane == 0) { a_s2[n] = ps; a_d2[n] = pd; }
}

// ============ fused per-node aggregation, layer 1 (8 heads x 8 ch) ============
// one wave per dst node; writes xh = elu(agg + b1) directly
__global__ __launch_bounds__(256) void agg1(const int* __restrict__ srclist,
                                            const int* __restrict__ offs,
                                            const int* __restrict__ deg,
                                            const float* __restrict__ a_s,
                                            const float* __restrict__ a_d,
                                            const float* __restrict__ h1,
                                            const float* __restrict__ b1,
                                            float* __restrict__ xh) {
    int wid  = (blockIdx.x * 256 + threadIdx.x) >> 6;   // node, 50000 waves exact
    int lane = threadIdx.x & 63;
    int d    = wid;
    int base = offs[d], dg = deg[d];
    int h   = lane & 7;      // phase-A head
    int sub = lane >> 3;     // phase-A edge-subset
    float ad_h = a_d[d * 8 + h];
    // A1: per-head max (self loop handled by sub==0)
    float mx = -1e30f;
    for (int k = sub; k < dg; k += 8)
        mx = fmaxf(mx, lrelu(a_s[srclist[base + k] * 8 + h] + ad_h));
    if (sub == 0) mx = fmaxf(mx, lrelu(a_s[d * 8 + h] + ad_h));
    mx = fmaxf(mx, __shfl_xor(mx, 8, 64));
    mx = fmaxf(mx, __shfl_xor(mx, 16, 64));
    mx = fmaxf(mx, __shfl_xor(mx, 32, 64));
    // A2: per-head sum of exp
    float sm = 0.f;
    for (int k = sub; k < dg; k += 8)
        sm += __expf(lrelu(a_s[srclist[base + k] * 8 + h] + ad_h) - mx);
    if (sub == 0) sm += __expf(lrelu(a_s[d * 8 + h] + ad_h) - mx);
    sm += __shfl_xor(sm, 8, 64);
    sm += __shfl_xor(sm, 16, 64);
    sm += __shfl_xor(sm, 32, 64);
    float inv = 1.f / (sm + 1e-16f);
    // B: accumulate channels; lane j = channel, head hj = j>>3
    int hj = lane >> 3;
    float mxB  = __shfl(mx, hj, 64);     // head hj's stats live at lane hj (sub=0,h=hj)
    float invB = __shfl(inv, hj, 64);
    float adB  = __shfl(ad_h, hj, 64);
    float acc = 0.f;
    for (int k = 0; k < dg; ++k) {
        int s = srclist[base + k];
        float alpha = __expf(lrelu(a_s[s * 8 + hj] + adB) - mxB) * invB;
        acc += h1[s * 64 + lane] * alpha;
    }
    {   // self loop
        float alpha = __expf(lrelu(a_s[d * 8 + hj] + adB) - mxB) * invB;
        acc += h1[d * 64 + lane] * alpha;
    }
    float v = acc + b1[lane];
    xh[d * 64 + lane] = v > 0.f ? v : expm1f(v);
}

// ============ fused per-node aggregation, layer 2 (1 head x 64 ch) ============
// writes out = agg + b2 directly
__global__ __launch_bounds__(256) void agg2(const int* __restrict__ srclist,
                                            const int* __restrict__ offs,
                                            const int* __restrict__ deg,
                                            const float* __restrict__ a_s,
                                            const float* __restrict__ a_d,
                                            const float* __restrict__ h2,
                                            const float* __restrict__ b2,
                                            float* __restrict__ out) {
    int wid  = (blockIdx.x * 256 + threadIdx.x) >> 6;
    int lane = threadIdx.x & 63;
    int d    = wid;
    int base = offs[d], dg = deg[d];
    float ad = a_d[d];
    float eself = lrelu(a_s[d] + ad);
    float mx = eself;                                    // self loop seeds max (all lanes)
    for (int k = lane; k < dg; k += 64)
        mx = fmaxf(mx, lrelu(a_s[srclist[base + k]] + ad));
#pragma unroll
    for (int m = 1; m < 64; m <<= 1) mx = fmaxf(mx, __shfl_xor(mx, m, 64));
    float sm = 0.f;
    for (int k = lane; k < dg; k += 64)
        sm += __expf(lrelu(a_s[srclist[base + k]] + ad) - mx);
#pragma unroll
    for (int m = 1; m < 64; m <<= 1) sm += __shfl_xor(sm, m, 64);
    sm += __expf(eself - mx);                            // self loop, same in all lanes
    float inv = 1.f / (sm + 1e-16f);
    float acc = 0.f;
    for (int k = 0; k < dg; ++k) {
        int s = srclist[base + k];
        float alpha = __expf(lrelu(a_s[s] + ad) - mx) * inv;
        acc += h2[s * 64 + lane] * alpha;
    }
    acc += h2[d * 64 + lane] * (__expf(eself - mx) * inv);
    out[d * 64 + lane] = acc + b2[lane];
}

extern "C" void kernel_launch(void* const* d_in, const int* in_sizes, int n_in,
                              void* d_out, int out_size, void* d_ws, size_t ws_size,
                              hipStream_t stream) {
    const float* x   = (const float*)d_in[0];
    const int*   ei  = (const int*)d_in[1];
    const float* W1  = (const float*)d_in[2];
    const float* as1 = (const float*)d_in[3];
    const float* ad1 = (const float*)d_in[4];
    const float* b1  = (const float*)d_in[5];
    const float* W2  = (const float*)d_in[6];
    const float* as2 = (const float*)d_in[7];
    const float* ad2 = (const float*)d_in[8];
    const float* b2  = (const float*)d_in[9];
    float* out = (float*)d_out;

    float* ws   = (float*)d_ws;
    float* h1   = ws;                        // 3,200,000
    float* h2   = h1 + 3200000;              // 3,200,000
    float* xh   = h2 + 3200000;              // 3,200,000
    float* a_s1 = xh + 3200000;              // 400,000
    float* a_d1 = a_s1 + 400000;             // 400,000
    float* a_s2 = a_d1 + 400000;             // 50,000
    float* a_d2 = a_s2 + 50000;              // 50,000
    int* deg     = (int*)(a_d2 + 50000);     // 50,000
    int* offs    = deg + 50000;              // 50,000
    int* cursor  = offs + 50000;             // 50,000
    int* bsum    = cursor + 50000;           // 256
    int* srclist = bsum + 256;               // 800,000

    // ---- CSR build (graph identical for both layers)
    hipMemsetAsync(deg, 0, (size_t)NN * 4, stream);
    hist<<<(NE + 255) / 256, 256, 0, stream>>>(ei, deg);
    scan1<<<256, 256, 0, stream>>>(deg, offs, bsum);
    scan2<<<1, 256, 0, stream>>>(bsum);
    scan3<<<(NN + 255) / 256, 256, 0, stream>>>(offs, bsum, cursor);
    scatter<<<(NE + 255) / 256, 256, 0, stream>>>(ei, cursor, srclist);

    // ---- layer 1
    gemm1<<<12500, 256, 0, stream>>>(x, W1, as1, ad1, h1, a_s1, a_d1);
    agg1<<<12500, 256, 0, stream>>>(srclist, offs, deg, a_s1, a_d1, h1, b1, xh);

    // ---- layer 2
    gemm2<<<12500, 256, 0, stream>>>(xh, W2, as2, ad2, h2, a_s2, a_d2);
    agg2<<<12500, 256, 0, stream>>>(srclist, offs, deg, a_s2, a_d2, h2, b2, out);
}

// Round 3
// 242.469 us; speedup vs baseline: 2.6727x; 1.5953x over previous
//
#include <hip/hip_runtime.h>

#define NN 50000
#define NE 800000
#define NEG_SLOPE 0.2f

__device__ __forceinline__ float lrelu(float v) { return v > 0.f ? v : NEG_SLOPE * v; }

// ============ CSR build (dst-sorted) ============
__global__ void hist(const int* __restrict__ ei, int* __restrict__ deg) {
    int e = blockIdx.x * blockDim.x + threadIdx.x;
    if (e < NE) atomicAdd(&deg[ei[NE + e]], 1);
}

__global__ __launch_bounds__(256) void scan1(const int* __restrict__ deg,
                                             int* __restrict__ offs, int* __restrict__ bsum) {
    __shared__ int tmp[256];
    int i = blockIdx.x * 256 + threadIdx.x;
    int v = (i < NN) ? deg[i] : 0;
    tmp[threadIdx.x] = v;
    __syncthreads();
    for (int o = 1; o < 256; o <<= 1) {
        int t = (threadIdx.x >= o) ? tmp[threadIdx.x - o] : 0;
        __syncthreads();
        tmp[threadIdx.x] += t;
        __syncthreads();
    }
    if (i < NN) offs[i] = tmp[threadIdx.x] - v;
    if (threadIdx.x == 255) bsum[blockIdx.x] = tmp[255];
}

__global__ __launch_bounds__(256) void scan2(int* __restrict__ bsum) {
    __shared__ int tmp[256];
    int v = bsum[threadIdx.x];
    tmp[threadIdx.x] = v;
    __syncthreads();
    for (int o = 1; o < 256; o <<= 1) {
        int t = (threadIdx.x >= o) ? tmp[threadIdx.x - o] : 0;
        __syncthreads();
        tmp[threadIdx.x] += t;
        __syncthreads();
    }
    bsum[threadIdx.x] = tmp[threadIdx.x] - v;
}

__global__ void scan3(int* __restrict__ offs, const int* __restrict__ bsum,
                      int* __restrict__ cursor) {
    int i = blockIdx.x * blockDim.x + threadIdx.x;
    if (i < NN) { int o = offs[i] + bsum[i >> 8]; offs[i] = o; cursor[i] = o; }
}

__global__ void scatter(const int* __restrict__ ei, int* __restrict__ cursor,
                        int* __restrict__ srclist) {
    int e = blockIdx.x * blockDim.x + threadIdx.x;
    if (e < NE) {
        int d = ei[NE + e];
        int pos = atomicAdd(&cursor[d], 1);
        srclist[pos] = ei[e];
    }
}

// ============ weight swizzle: W[k,c] -> WS[(k4*64+c)*4+j], k=4*k4+j ============
// makes per-k4 wave loads of float4 per lane fully coalesced (1 KB / instr)
__global__ void prep(const float* __restrict__ W1, const float* __restrict__ W2,
                     float* __restrict__ W1S, float* __restrict__ W2S) {
    int tid = blockIdx.x * blockDim.x + threadIdx.x;
    if (tid < 8192) {                       // W1: 128x64
        int k = tid >> 6, c = tid & 63;
        W1S[((k >> 2) * 64 + c) * 4 + (k & 3)] = W1[k * 64 + c];
    } else if (tid < 12288) {               // W2: 64x64
        int t = tid - 8192;
        int k = t >> 6, c = t & 63;
        W2S[((k >> 2) * 64 + c) * 4 + (k & 3)] = W2[k * 64 + c];
    }
}

// ============ gemm1: h1 = x @ W1, fused logits (8 heads x 8 ch) ============
__global__ __launch_bounds__(256) void gemm1(const float* __restrict__ x,
                                             const float* __restrict__ W1S,
                                             const float* __restrict__ att_s,
                                             const float* __restrict__ att_d,
                                             float* __restrict__ h1,
                                             float* __restrict__ a_s,
                                             float* __restrict__ a_d) {
    __shared__ float4 xs4[4][32];
    int lane = threadIdx.x & 63;
    int row  = threadIdx.x >> 6;
    int n    = blockIdx.x * 4 + row;
    if (lane < 32) xs4[row][lane] = ((const float4*)&x[n * 128])[lane];
    __syncthreads();
    const float4* wp = (const float4*)W1S;
    float acc = 0.f;
#pragma unroll
    for (int k4 = 0; k4 < 32; ++k4) {
        float4 w  = wp[k4 * 64 + lane];
        float4 xv = xs4[row][k4];
        acc += xv.x * w.x + xv.y * w.y + xv.z * w.z + xv.w * w.w;
    }
    h1[n * 64 + lane] = acc;
    float ps = acc * att_s[lane];
    float pd = acc * att_d[lane];
#pragma unroll
    for (int m = 1; m < 8; m <<= 1) { ps += __shfl_xor(ps, m, 64); pd += __shfl_xor(pd, m, 64); }
    if ((lane & 7) == 0) { int h = lane >> 3; a_s[n * 8 + h] = ps; a_d[n * 8 + h] = pd; }
}

// ============ agg1 + fused gemm2 ============
// one wave per node. single-pass softmax (stabilized by self-loop logit):
// out_c = (sum_e exp(e)*h_c) / (sum_e exp(e)); then h2 = elu(out+b1) @ W2 + logits2
__global__ __launch_bounds__(256) void agg1(const int* __restrict__ srclist,
                                            const int* __restrict__ offs,
                                            const int* __restrict__ deg,
                                            const float* __restrict__ a_s,
                                            const float* __restrict__ a_d,
                                            const float* __restrict__ h1,
                                            const float* __restrict__ b1,
                                            const float* __restrict__ W2S,
                                            const float* __restrict__ as2v,
                                            const float* __restrict__ ad2v,
                                            float* __restrict__ h2,
                                            float* __restrict__ a_s2,
                                            float* __restrict__ a_d2) {
    int wid  = (blockIdx.x * 256 + threadIdx.x) >> 6;
    int lane = threadIdx.x & 63;
    int d    = wid;
    int base = offs[d], dg = deg[d];
    int sub  = lane >> 4;          // edge subset 0..3
    int cl   = lane & 15;          // channel group: channels 4cl..4cl+3
    int h    = cl >> 1;            // head of this channel group
    float adh   = a_d[d * 8 + h];
    float eself = lrelu(a_s[d * 8 + h] + adh);
    float4 acc = {0.f, 0.f, 0.f, 0.f};
    float  sm  = 0.f;
#pragma unroll 2
    for (int k = sub; k < dg; k += 4) {
        int s = srclist[base + k];
        float ex = __expf(lrelu(a_s[s * 8 + h] + adh) - eself);
        float4 hv = *(const float4*)&h1[s * 64 + 4 * cl];
        acc.x += hv.x * ex; acc.y += hv.y * ex; acc.z += hv.z * ex; acc.w += hv.w * ex;
        sm += ex;
    }
    if (sub == 0) {                // self loop: exp(eself - eself) = 1
        float4 hv = *(const float4*)&h1[d * 64 + 4 * cl];
        acc.x += hv.x; acc.y += hv.y; acc.z += hv.z; acc.w += hv.w;
        sm += 1.f;
    }
#pragma unroll
    for (int m = 16; m < 64; m <<= 1) {
        acc.x += __shfl_xor(acc.x, m, 64);
        acc.y += __shfl_xor(acc.y, m, 64);
        acc.z += __shfl_xor(acc.z, m, 64);
        acc.w += __shfl_xor(acc.w, m, 64);
        sm    += __shfl_xor(sm, m, 64);
    }
    float inv = 1.f / sm;
    float4 bv = *(const float4*)&b1[4 * cl];
    float4 v;
    v.x = acc.x * inv + bv.x; v.x = v.x > 0.f ? v.x : expm1f(v.x);
    v.y = acc.y * inv + bv.y; v.y = v.y > 0.f ? v.y : expm1f(v.y);
    v.z = acc.z * inv + bv.z; v.z = v.z > 0.f ? v.z : expm1f(v.z);
    v.w = acc.w * inv + bv.w; v.w = v.w > 0.f ? v.w : expm1f(v.w);
    // ---- fused gemm2: every lane computes h2[d, lane]; xh row broadcast via readlane
    const float4* wp = (const float4*)W2S;
    float acc2 = 0.f;
#pragma unroll
    for (int k4 = 0; k4 < 16; ++k4) {
        float4 w = wp[k4 * 64 + lane];
        acc2 += __shfl(v.x, k4, 64) * w.x + __shfl(v.y, k4, 64) * w.y
              + __shfl(v.z, k4, 64) * w.z + __shfl(v.w, k4, 64) * w.w;
    }
    h2[d * 64 + lane] = acc2;
    float ps = acc2 * as2v[lane];
    float pd = acc2 * ad2v[lane];
#pragma unroll
    for (int m = 1; m < 64; m <<= 1) { ps += __shfl_xor(ps, m, 64); pd += __shfl_xor(pd, m, 64); }
    if (lane == 0) { a_s2[d] = ps; a_d2[d] = pd; }
}

// ============ agg2: single-pass, 1 head x 64 ch, writes out + b2 ============
__global__ __launch_bounds__(256) void agg2(const int* __restrict__ srclist,
                                            const int* __restrict__ offs,
                                            const int* __restrict__ deg,
                                            const float* __restrict__ a_s,
                                            const float* __restrict__ a_d,
                                            const float* __restrict__ h2,
                                            const float* __restrict__ b2,
                                            float* __restrict__ out) {
    int wid  = (blockIdx.x * 256 + threadIdx.x) >> 6;
    int lane = threadIdx.x & 63;
    int d    = wid;
    int base = offs[d], dg = deg[d];
    int sub  = lane >> 4;
    int cl   = lane & 15;
    float ad    = a_d[d];
    float eself = lrelu(a_s[d] + ad);
    float4 acc = {0.f, 0.f, 0.f, 0.f};
    float  sm  = 0.f;
#pragma unroll 2
    for (int k = sub; k < dg; k += 4) {
        int s = srclist[base + k];
        float ex = __expf(lrelu(a_s[s] + ad) - eself);
        float4 hv = *(const float4*)&h2[s * 64 + 4 * cl];
        acc.x += hv.x * ex; acc.y += hv.y * ex; acc.z += hv.z * ex; acc.w += hv.w * ex;
        sm += ex;
    }
    if (sub == 0) {
        float4 hv = *(const float4*)&h2[d * 64 + 4 * cl];
        acc.x += hv.x; acc.y += hv.y; acc.z += hv.z; acc.w += hv.w;
        sm += 1.f;
    }
#pragma unroll
    for (int m = 16; m < 64; m <<= 1) {
        acc.x += __shfl_xor(acc.x, m, 64);
        acc.y += __shfl_xor(acc.y, m, 64);
        acc.z += __shfl_xor(acc.z, m, 64);
        acc.w += __shfl_xor(acc.w, m, 64);
        sm    += __shfl_xor(sm, m, 64);
    }
    if (sub == 0) {
        float inv = 1.f / sm;
        float4 bv = *(const float4*)&b2[4 * cl];
        float4 o;
        o.x = acc.x * inv + bv.x;
        o.y = acc.y * inv + bv.y;
        o.z = acc.z * inv + bv.z;
        o.w = acc.w * inv + bv.w;
        *(float4*)&out[d * 64 + 4 * cl] = o;
    }
}

extern "C" void kernel_launch(void* const* d_in, const int* in_sizes, int n_in,
                              void* d_out, int out_size, void* d_ws, size_t ws_size,
                              hipStream_t stream) {
    const float* x   = (const float*)d_in[0];
    const int*   ei  = (const int*)d_in[1];
    const float* W1  = (const float*)d_in[2];
    const float* as1 = (const float*)d_in[3];
    const float* ad1 = (const float*)d_in[4];
    const float* b1  = (const float*)d_in[5];
    const float* W2  = (const float*)d_in[6];
    const float* as2 = (const float*)d_in[7];
    const float* ad2 = (const float*)d_in[8];
    const float* b2  = (const float*)d_in[9];
    float* out = (float*)d_out;

    float* ws   = (float*)d_ws;
    float* h1   = ws;                        // 3,200,000
    float* h2   = h1 + 3200000;              // 3,200,000
    float* a_s1 = h2 + 3200000;              // 400,000
    float* a_d1 = a_s1 + 400000;             // 400,000
    float* a_s2 = a_d1 + 400000;             // 50,000
    float* a_d2 = a_s2 + 50000;              // 50,000
    int* deg     = (int*)(a_d2 + 50000);     // 50,000
    int* offs    = deg + 50000;              // 50,000
    int* cursor  = offs + 50000;             // 50,000
    int* bsum    = cursor + 50000;           // 256
    int* srclist = bsum + 256;               // 800,000
    float* W1S   = (float*)(srclist + 800000); // 8,192
    float* W2S   = W1S + 8192;               // 4,096

    // ---- CSR build + weight swizzle
    hipMemsetAsync(deg, 0, (size_t)NN * 4, stream);
    hist<<<(NE + 255) / 256, 256, 0, stream>>>(ei, deg);
    prep<<<48, 256, 0, stream>>>(W1, W2, W1S, W2S);
    scan1<<<256, 256, 0, stream>>>(deg, offs, bsum);
    scan2<<<1, 256, 0, stream>>>(bsum);
    scan3<<<(NN + 255) / 256, 256, 0, stream>>>(offs, bsum, cursor);
    scatter<<<(NE + 255) / 256, 256, 0, stream>>>(ei, cursor, srclist);

    // ---- layer 1 GEMM
    gemm1<<<12500, 256, 0, stream>>>(x, W1S, as1, ad1, h1, a_s1, a_d1);
    // ---- layer 1 aggregate + fused layer 2 GEMM/logits
    agg1<<<12500, 256, 0, stream>>>(srclist, offs, deg, a_s1, a_d1, h1, b1,
                                    W2S, as2, ad2, h2, a_s2, a_d2);
    // ---- layer 2 aggregate
    agg2<<<12500, 256, 0, stream>>>(srclist, offs, deg, a_s2, a_d2, h2, b2, out);
}

// Round 4
// 221.885 us; speedup vs baseline: 2.9207x; 1.0928x over previous
//
#include <hip/hip_runtime.h>

#define NN 50000
#define NE 800000
#define NEG_SLOPE 0.2f

__device__ __forceinline__ float lrelu(float v) { return v > 0.f ? v : NEG_SLOPE * v; }
__device__ __forceinline__ float bf2f(unsigned short u) { return __uint_as_float((unsigned)u << 16); }
__device__ __forceinline__ unsigned short f2bf(float f) {
    unsigned u = __float_as_uint(f);
    return (unsigned short)((u + 0x7FFFu + ((u >> 16) & 1u)) >> 16);   // RNE
}
__device__ __forceinline__ float rlane(float v, int l) {
    return __int_as_float(__builtin_amdgcn_readlane(__float_as_int(v), l));
}

// ============ CSR build (dst-sorted) ============
__global__ void hist(const int* __restrict__ ei, int* __restrict__ deg) {
    int e = blockIdx.x * blockDim.x + threadIdx.x;
    if (e < NE) atomicAdd(&deg[ei[NE + e]], 1);
}

__global__ __launch_bounds__(256) void scan1(const int* __restrict__ deg,
                                             int* __restrict__ offs, int* __restrict__ bsum) {
    __shared__ int tmp[256];
    int i = blockIdx.x * 256 + threadIdx.x;
    int v = (i < NN) ? deg[i] : 0;
    tmp[threadIdx.x] = v;
    __syncthreads();
    for (int o = 1; o < 256; o <<= 1) {
        int t = (threadIdx.x >= o) ? tmp[threadIdx.x - o] : 0;
        __syncthreads();
        tmp[threadIdx.x] += t;
        __syncthreads();
    }
    if (i < NN) offs[i] = tmp[threadIdx.x] - v;
    if (threadIdx.x == 255) bsum[blockIdx.x] = tmp[255];
}

__global__ __launch_bounds__(256) void scan2(int* __restrict__ bsum) {
    __shared__ int tmp[256];
    int v = bsum[threadIdx.x];
    tmp[threadIdx.x] = v;
    __syncthreads();
    for (int o = 1; o < 256; o <<= 1) {
        int t = (threadIdx.x >= o) ? tmp[threadIdx.x - o] : 0;
        __syncthreads();
        tmp[threadIdx.x] += t;
        __syncthreads();
    }
    bsum[threadIdx.x] = tmp[threadIdx.x] - v;
}

__global__ void scan3(int* __restrict__ offs, const int* __restrict__ bsum,
                      int* __restrict__ cursor) {
    int i = blockIdx.x * blockDim.x + threadIdx.x;
    if (i < NN) { int o = offs[i] + bsum[i >> 8]; offs[i] = o; cursor[i] = o; }
}

__global__ void scatter(const int* __restrict__ ei, int* __restrict__ cursor,
                        int* __restrict__ srclist) {
    int e = blockIdx.x * blockDim.x + threadIdx.x;
    if (e < NE) {
        int d = ei[NE + e];
        int pos = atomicAdd(&cursor[d], 1);
        srclist[pos] = ei[e];
    }
}

// ============ weight swizzle: W[k,c] -> WS[(k4*64+c)*4+j], k=4*k4+j ============
__global__ void prep(const float* __restrict__ W1, const float* __restrict__ W2,
                     float* __restrict__ W1S, float* __restrict__ W2S) {
    int tid = blockIdx.x * blockDim.x + threadIdx.x;
    if (tid < 8192) {
        int k = tid >> 6, c = tid & 63;
        W1S[((k >> 2) * 64 + c) * 4 + (k & 3)] = W1[k * 64 + c];
    } else if (tid < 12288) {
        int t = tid - 8192;
        int k = t >> 6, c = t & 63;
        W2S[((k >> 2) * 64 + c) * 4 + (k & 3)] = W2[k * 64 + c];
    }
}

// ============ gemm1: h1 = x @ W1 (bf16 out), fused logits ============
// 4 waves/block, 4 nodes/wave: x rows via SCALAR loads (uniform ptr), W via L1 vector loads
__global__ __launch_bounds__(256) void gemm1(const float* __restrict__ x,
                                             const float* __restrict__ W1S,
                                             const float* __restrict__ att_s,
                                             const float* __restrict__ att_d,
                                             unsigned short* __restrict__ h1b,
                                             float* __restrict__ a_s,
                                             float* __restrict__ a_d) {
    int lane = threadIdx.x & 63;
    int wv   = __builtin_amdgcn_readfirstlane(threadIdx.x >> 6);   // uniform wave id
    int n0   = blockIdx.x * 16 + wv * 4;                            // uniform
    const float* __restrict__ xr = x + (size_t)n0 * 128;            // uniform ptr -> s_load
    const float4* __restrict__ wp = (const float4*)W1S;
    float4 acc = {0.f, 0.f, 0.f, 0.f};
#pragma unroll 4
    for (int k4 = 0; k4 < 32; ++k4) {
        float4 w = wp[k4 * 64 + lane];
        const float* xk = xr + k4 * 4;
        acc.x += xk[0]   * w.x + xk[1]   * w.y + xk[2]   * w.z + xk[3]   * w.w;
        acc.y += xk[128] * w.x + xk[129] * w.y + xk[130] * w.z + xk[131] * w.w;
        acc.z += xk[256] * w.x + xk[257] * w.y + xk[258] * w.z + xk[259] * w.w;
        acc.w += xk[384] * w.x + xk[385] * w.y + xk[386] * w.z + xk[387] * w.w;
    }
    float as_l = att_s[lane], ad_l = att_d[lane];
    float av[4] = {acc.x, acc.y, acc.z, acc.w};
#pragma unroll
    for (int r = 0; r < 4; ++r) {
        float a = av[r];
        h1b[(size_t)(n0 + r) * 64 + lane] = f2bf(a);
        float ps = a * as_l, pd = a * ad_l;
        ps += __shfl_xor(ps, 1, 64); pd += __shfl_xor(pd, 1, 64);
        ps += __shfl_xor(ps, 2, 64); pd += __shfl_xor(pd, 2, 64);
        ps += __shfl_xor(ps, 4, 64); pd += __shfl_xor(pd, 4, 64);
        if ((lane & 7) == 0) {
            a_s[(n0 + r) * 8 + (lane >> 3)] = ps;
            a_d[(n0 + r) * 8 + (lane >> 3)] = pd;
        }
    }
}

// ============ agg1 + fused gemm2 (bf16 gather, bf16 h2 out) ============
__global__ __launch_bounds__(256) void agg1(const int* __restrict__ srclist,
                                            const int* __restrict__ offs,
                                            const int* __restrict__ deg,
                                            const float* __restrict__ a_s,
                                            const float* __restrict__ a_d,
                                            const unsigned short* __restrict__ h1b,
                                            const float* __restrict__ b1,
                                            const float* __restrict__ W2S,
                                            const float* __restrict__ as2v,
                                            const float* __restrict__ ad2v,
                                            unsigned short* __restrict__ h2b,
                                            float* __restrict__ a_s2,
                                            float* __restrict__ a_d2) {
    int wid  = (blockIdx.x * 256 + threadIdx.x) >> 6;
    int lane = threadIdx.x & 63;
    int d    = wid;
    int base = offs[d], dg = deg[d];
    int sub  = lane >> 4;          // edge subset 0..3
    int cl   = lane & 15;          // channel group (4 ch)
    int h    = cl >> 1;            // head
    float adh   = a_d[d * 8 + h];
    float eself = lrelu(a_s[d * 8 + h] + adh);
    float4 acc = {0.f, 0.f, 0.f, 0.f};
    float  sm  = 0.f;
#pragma unroll 4
    for (int k = sub; k < dg; k += 4) {
        int s = srclist[base + k];
        float ex = __expf(lrelu(a_s[s * 8 + h] + adh) - eself);
        ushort4 hv = *(const ushort4*)&h1b[(size_t)s * 64 + 4 * cl];
        acc.x += bf2f(hv.x) * ex; acc.y += bf2f(hv.y) * ex;
        acc.z += bf2f(hv.z) * ex; acc.w += bf2f(hv.w) * ex;
        sm += ex;
    }
    if (sub == 0) {                 // self loop: exp(0) = 1
        ushort4 hv = *(const ushort4*)&h1b[(size_t)d * 64 + 4 * cl];
        acc.x += bf2f(hv.x); acc.y += bf2f(hv.y);
        acc.z += bf2f(hv.z); acc.w += bf2f(hv.w);
        sm += 1.f;
    }
#pragma unroll
    for (int m = 16; m < 64; m <<= 1) {
        acc.x += __shfl_xor(acc.x, m, 64);
        acc.y += __shfl_xor(acc.y, m, 64);
        acc.z += __shfl_xor(acc.z, m, 64);
        acc.w += __shfl_xor(acc.w, m, 64);
        sm    += __shfl_xor(sm, m, 64);
    }
    float inv = 1.f / sm;
    float4 bv = *(const float4*)&b1[4 * cl];
    float4 v;
    v.x = acc.x * inv + bv.x; v.x = v.x > 0.f ? v.x : expm1f(v.x);
    v.y = acc.y * inv + bv.y; v.y = v.y > 0.f ? v.y : expm1f(v.y);
    v.z = acc.z * inv + bv.z; v.z = v.z > 0.f ? v.z : expm1f(v.z);
    v.w = acc.w * inv + bv.w; v.w = v.w > 0.f ? v.w : expm1f(v.w);
    // ---- fused gemm2 via readlane broadcasts (no LDS / bpermute)
    const float4* wp = (const float4*)W2S;
    float acc2 = 0.f;
#pragma unroll
    for (int k4 = 0; k4 < 16; ++k4) {
        float4 w = wp[k4 * 64 + lane];
        acc2 += rlane(v.x, k4) * w.x + rlane(v.y, k4) * w.y
              + rlane(v.z, k4) * w.z + rlane(v.w, k4) * w.w;
    }
    h2b[(size_t)d * 64 + lane] = f2bf(acc2);
    float ps = acc2 * as2v[lane];
    float pd = acc2 * ad2v[lane];
#pragma unroll
    for (int m = 1; m < 64; m <<= 1) { ps += __shfl_xor(ps, m, 64); pd += __shfl_xor(pd, m, 64); }
    if (lane == 0) { a_s2[d] = ps; a_d2[d] = pd; }
}

// ============ agg2: single-pass, bf16 gather, writes out + b2 ============
__global__ __launch_bounds__(256) void agg2(const int* __restrict__ srclist,
                                            const int* __restrict__ offs,
                                            const int* __restrict__ deg,
                                            const float* __restrict__ a_s,
                                            const float* __restrict__ a_d,
                                            const unsigned short* __restrict__ h2b,
                                            const float* __restrict__ b2,
                                            float* __restrict__ out) {
    int wid  = (blockIdx.x * 256 + threadIdx.x) >> 6;
    int lane = threadIdx.x & 63;
    int d    = wid;
    int base = offs[d], dg = deg[d];
    int sub  = lane >> 4;
    int cl   = lane & 15;
    float ad    = a_d[d];
    float eself = lrelu(a_s[d] + ad);
    float4 acc = {0.f, 0.f, 0.f, 0.f};
    float  sm  = 0.f;
#pragma unroll 4
    for (int k = sub; k < dg; k += 4) {
        int s = srclist[base + k];
        float ex = __expf(lrelu(a_s[s] + ad) - eself);
        ushort4 hv = *(const ushort4*)&h2b[(size_t)s * 64 + 4 * cl];
        acc.x += bf2f(hv.x) * ex; acc.y += bf2f(hv.y) * ex;
        acc.z += bf2f(hv.z) * ex; acc.w += bf2f(hv.w) * ex;
        sm += ex;
    }
    if (sub == 0) {
        ushort4 hv = *(const ushort4*)&h2b[(size_t)d * 64 + 4 * cl];
        acc.x += bf2f(hv.x); acc.y += bf2f(hv.y);
        acc.z += bf2f(hv.z); acc.w += bf2f(hv.w);
        sm += 1.f;
    }
#pragma unroll
    for (int m = 16; m < 64; m <<= 1) {
        acc.x += __shfl_xor(acc.x, m, 64);
        acc.y += __shfl_xor(acc.y, m, 64);
        acc.z += __shfl_xor(acc.z, m, 64);
        acc.w += __shfl_xor(acc.w, m, 64);
        sm    += __shfl_xor(sm, m, 64);
    }
    if (sub == 0) {
        float inv = 1.f / sm;
        float4 bv = *(const float4*)&b2[4 * cl];
        float4 o;
        o.x = acc.x * inv + bv.x;
        o.y = acc.y * inv + bv.y;
        o.z = acc.z * inv + bv.z;
        o.w = acc.w * inv + bv.w;
        *(float4*)&out[d * 64 + 4 * cl] = o;
    }
}

extern "C" void kernel_launch(void* const* d_in, const int* in_sizes, int n_in,
                              void* d_out, int out_size, void* d_ws, size_t ws_size,
                              hipStream_t stream) {
    const float* x   = (const float*)d_in[0];
    const int*   ei  = (const int*)d_in[1];
    const float* W1  = (const float*)d_in[2];
    const float* as1 = (const float*)d_in[3];
    const float* ad1 = (const float*)d_in[4];
    const float* b1  = (const float*)d_in[5];
    const float* W2  = (const float*)d_in[6];
    const float* as2 = (const float*)d_in[7];
    const float* ad2 = (const float*)d_in[8];
    const float* b2  = (const float*)d_in[9];
    float* out = (float*)d_out;

    float* ws = (float*)d_ws;
    unsigned short* h1b = (unsigned short*)ws;             // 3.2M ushort (1.6M floats)
    unsigned short* h2b = (unsigned short*)(ws + 1600000); // 3.2M ushort
    float* a_s1 = ws + 3200000;              // 400,000
    float* a_d1 = a_s1 + 400000;             // 400,000
    float* a_s2 = a_d1 + 400000;             // 50,000
    float* a_d2 = a_s2 + 50000;              // 50,000
    int* deg     = (int*)(a_d2 + 50000);     // 50,000
    int* offs    = deg + 50000;              // 50,000
    int* cursor  = offs + 50000;             // 50,000
    int* bsum    = cursor + 50000;           // 256
    int* srclist = bsum + 256;               // 800,000
    float* W1S   = (float*)(srclist + 800000); // 8,192
    float* W2S   = W1S + 8192;               // 4,096

    // ---- CSR build + weight swizzle
    hipMemsetAsync(deg, 0, (size_t)NN * 4, stream);
    hist<<<(NE + 255) / 256, 256, 0, stream>>>(ei, deg);
    prep<<<48, 256, 0, stream>>>(W1, W2, W1S, W2S);
    scan1<<<256, 256, 0, stream>>>(deg, offs, bsum);
    scan2<<<1, 256, 0, stream>>>(bsum);
    scan3<<<(NN + 255) / 256, 256, 0, stream>>>(offs, bsum, cursor);
    scatter<<<(NE + 255) / 256, 256, 0, stream>>>(ei, cursor, srclist);

    // ---- layer 1 GEMM (16 nodes/block)
    gemm1<<<3125, 256, 0, stream>>>(x, W1S, as1, ad1, h1b, a_s1, a_d1);
    // ---- layer 1 aggregate + fused layer 2 GEMM/logits
    agg1<<<12500, 256, 0, stream>>>(srclist, offs, deg, a_s1, a_d1, h1b, b1,
                                    W2S, as2, ad2, h2b, a_s2, a_d2);
    // ---- layer 2 aggregate
    agg2<<<12500, 256, 0, stream>>>(srclist, offs, deg, a_s2, a_d2, h2b, b2, out);
}

// Round 5
// 220.647 us; speedup vs baseline: 2.9371x; 1.0056x over previous
//
#include <hip/hip_runtime.h>

#define NN 50000
#define NE 800000
#define NEG_SLOPE 0.2f
#define CHUNK 64

__device__ __forceinline__ float lrelu(float v) { return v > 0.f ? v : NEG_SLOPE * v; }
__device__ __forceinline__ float bf2f(unsigned short u) { return __uint_as_float((unsigned)u << 16); }
__device__ __forceinline__ unsigned short f2bf(float f) {
    unsigned u = __float_as_uint(f);
    return (unsigned short)((u + 0x7FFFu + ((u >> 16) & 1u)) >> 16);   // RNE
}
__device__ __forceinline__ float rlane(float v, int l) {
    return __int_as_float(__builtin_amdgcn_readlane(__float_as_int(v), l));
}
__device__ __forceinline__ void lds_fence() {
    asm volatile("s_waitcnt lgkmcnt(0)" ::: "memory");
    __builtin_amdgcn_wave_barrier();
}

// ============ CSR build (dst-sorted) ============
__global__ void hist(const int* __restrict__ ei, int* __restrict__ deg) {
    int e = blockIdx.x * blockDim.x + threadIdx.x;
    if (e < NE) atomicAdd(&deg[ei[NE + e]], 1);
}

__global__ __launch_bounds__(256) void scan1(const int* __restrict__ deg,
                                             int* __restrict__ offs, int* __restrict__ bsum) {
    __shared__ int tmp[256];
    int i = blockIdx.x * 256 + threadIdx.x;
    int v = (i < NN) ? deg[i] : 0;
    tmp[threadIdx.x] = v;
    __syncthreads();
    for (int o = 1; o < 256; o <<= 1) {
        int t = (threadIdx.x >= o) ? tmp[threadIdx.x - o] : 0;
        __syncthreads();
        tmp[threadIdx.x] += t;
        __syncthreads();
    }
    if (i < NN) offs[i] = tmp[threadIdx.x] - v;
    if (threadIdx.x == 255) bsum[blockIdx.x] = tmp[255];
}

__global__ __launch_bounds__(256) void scan2(int* __restrict__ bsum) {
    __shared__ int tmp[256];
    int v = bsum[threadIdx.x];
    tmp[threadIdx.x] = v;
    __syncthreads();
    for (int o = 1; o < 256; o <<= 1) {
        int t = (threadIdx.x >= o) ? tmp[threadIdx.x - o] : 0;
        __syncthreads();
        tmp[threadIdx.x] += t;
        __syncthreads();
    }
    bsum[threadIdx.x] = tmp[threadIdx.x] - v;
}

__global__ void scan3(int* __restrict__ offs, const int* __restrict__ bsum,
                      int* __restrict__ cursor) {
    int i = blockIdx.x * blockDim.x + threadIdx.x;
    if (i < NN) { int o = offs[i] + bsum[i >> 8]; offs[i] = o; cursor[i] = o; }
}

__global__ void scatter(const int* __restrict__ ei, int* __restrict__ cursor,
                        int* __restrict__ srclist) {
    int e = blockIdx.x * blockDim.x + threadIdx.x;
    if (e < NE) {
        int d = ei[NE + e];
        int pos = atomicAdd(&cursor[d], 1);
        srclist[pos] = ei[e];
    }
}

// ============ weight swizzle: W[k,c] -> WS[(k4*64+c)*4+j], k=4*k4+j ============
__global__ void prep(const float* __restrict__ W1, const float* __restrict__ W2,
                     float* __restrict__ W1S, float* __restrict__ W2S) {
    int tid = blockIdx.x * blockDim.x + threadIdx.x;
    if (tid < 8192) {
        int k = tid >> 6, c = tid & 63;
        W1S[((k >> 2) * 64 + c) * 4 + (k & 3)] = W1[k * 64 + c];
    } else if (tid < 12288) {
        int t = tid - 8192;
        int k = t >> 6, c = t & 63;
        W2S[((k >> 2) * 64 + c) * 4 + (k & 3)] = W2[k * 64 + c];
    }
}

// ============ gemm1: h1 = x @ W1 (bf16 out), fused logits ============
__global__ __launch_bounds__(256) void gemm1(const float* __restrict__ x,
                                             const float* __restrict__ W1S,
                                             const float* __restrict__ att_s,
                                             const float* __restrict__ att_d,
                                             unsigned short* __restrict__ h1b,
                                             float* __restrict__ a_s,
                                             float* __restrict__ a_d) {
    int lane = threadIdx.x & 63;
    int wv   = __builtin_amdgcn_readfirstlane(threadIdx.x >> 6);
    int n0   = blockIdx.x * 16 + wv * 4;
    const float* __restrict__ xr = x + (size_t)n0 * 128;            // uniform ptr -> s_load
    const float4* __restrict__ wp = (const float4*)W1S;
    float4 acc = {0.f, 0.f, 0.f, 0.f};
#pragma unroll 4
    for (int k4 = 0; k4 < 32; ++k4) {
        float4 w = wp[k4 * 64 + lane];
        const float* xk = xr + k4 * 4;
        acc.x += xk[0]   * w.x + xk[1]   * w.y + xk[2]   * w.z + xk[3]   * w.w;
        acc.y += xk[128] * w.x + xk[129] * w.y + xk[130] * w.z + xk[131] * w.w;
        acc.z += xk[256] * w.x + xk[257] * w.y + xk[258] * w.z + xk[259] * w.w;
        acc.w += xk[384] * w.x + xk[385] * w.y + xk[386] * w.z + xk[387] * w.w;
    }
    float as_l = att_s[lane], ad_l = att_d[lane];
    float av[4] = {acc.x, acc.y, acc.z, acc.w};
#pragma unroll
    for (int r = 0; r < 4; ++r) {
        float a = av[r];
        h1b[(size_t)(n0 + r) * 64 + lane] = f2bf(a);
        float ps = a * as_l, pd = a * ad_l;
        ps += __shfl_xor(ps, 1, 64); pd += __shfl_xor(pd, 1, 64);
        ps += __shfl_xor(ps, 2, 64); pd += __shfl_xor(pd, 2, 64);
        ps += __shfl_xor(ps, 4, 64); pd += __shfl_xor(pd, 4, 64);
        if ((lane & 7) == 0) {
            a_s[(n0 + r) * 8 + (lane >> 3)] = ps;
            a_d[(n0 + r) * 8 + (lane >> 3)] = pd;
        }
    }
}

// ============ agg1 + fused gemm2: two-phase LDS-staged ============
__global__ __launch_bounds__(256) void agg1(const int* __restrict__ srclist,
                                            const int* __restrict__ offs,
                                            const int* __restrict__ deg,
                                            const float* __restrict__ a_s,
                                            const float* __restrict__ a_d,
                                            const unsigned short* __restrict__ h1b,
                                            const float* __restrict__ b1,
                                            const float* __restrict__ W2S,
                                            const float* __restrict__ as2v,
                                            const float* __restrict__ ad2v,
                                            unsigned short* __restrict__ h2b,
                                            float* __restrict__ a_s2,
                                            float* __restrict__ a_d2) {
    __shared__ int   sidxL[4][CHUNK];
    __shared__ float exL[4][CHUNK][8];
    int wv   = threadIdx.x >> 6;
    int lane = threadIdx.x & 63;
    int d    = blockIdx.x * 4 + wv;
    int base = offs[d], dg = deg[d];
    // phase-1 per-lane head constants (lane handles head h1p of edge lane>>3 + 8k)
    int   h1p  = lane & 7;
    float adh1 = a_d[d * 8 + h1p];
    float es1  = lrelu(a_s[d * 8 + h1p] + adh1);   // per-head self-logit stabilizer
    // phase-2 mapping
    int sub = lane >> 4, cl = lane & 15, h2p = cl >> 1;
    float4 acc = {0.f, 0.f, 0.f, 0.f};
    float  sm  = 0.f;

    for (int c0 = 0; c0 < dg; c0 += CHUNK) {
        int cnt = min(CHUNK, dg - c0);
        // ---- phase 1: 8 lanes/edge, 1 exp/lane
        for (int e = lane >> 3; e < cnt; e += 8) {
            int s = srclist[base + c0 + e];
            float ex = __expf(lrelu(a_s[s * 8 + h1p] + adh1) - es1);
            exL[wv][e][h1p] = ex;
            if (h1p == 0) sidxL[wv][e] = s;
        }
        lds_fence();
        // ---- phase 2: 4 edges/iter, gather addresses depend only on LDS
#pragma unroll 4
        for (int k = sub; k < cnt; k += 4) {
            int   s  = sidxL[wv][k];
            float ex = exL[wv][k][h2p];
            ushort4 hv = *(const ushort4*)&h1b[(size_t)s * 64 + 4 * cl];
            acc.x += bf2f(hv.x) * ex; acc.y += bf2f(hv.y) * ex;
            acc.z += bf2f(hv.z) * ex; acc.w += bf2f(hv.w) * ex;
            sm += ex;
        }
        __builtin_amdgcn_wave_barrier();
    }
    if (sub == 0) {                 // self loop: exp(es - es) = 1
        ushort4 hv = *(const ushort4*)&h1b[(size_t)d * 64 + 4 * cl];
        acc.x += bf2f(hv.x); acc.y += bf2f(hv.y);
        acc.z += bf2f(hv.z); acc.w += bf2f(hv.w);
        sm += 1.f;
    }
#pragma unroll
    for (int m = 16; m < 64; m <<= 1) {
        acc.x += __shfl_xor(acc.x, m, 64);
        acc.y += __shfl_xor(acc.y, m, 64);
        acc.z += __shfl_xor(acc.z, m, 64);
        acc.w += __shfl_xor(acc.w, m, 64);
        sm    += __shfl_xor(sm, m, 64);
    }
    float inv = 1.f / sm;
    float4 bv = *(const float4*)&b1[4 * cl];
    float4 v;
    v.x = acc.x * inv + bv.x; v.x = v.x > 0.f ? v.x : expm1f(v.x);
    v.y = acc.y * inv + bv.y; v.y = v.y > 0.f ? v.y : expm1f(v.y);
    v.z = acc.z * inv + bv.z; v.z = v.z > 0.f ? v.z : expm1f(v.z);
    v.w = acc.w * inv + bv.w; v.w = v.w > 0.f ? v.w : expm1f(v.w);
    // ---- fused gemm2 via readlane broadcasts
    const float4* wp = (const float4*)W2S;
    float acc2 = 0.f;
#pragma unroll
    for (int k4 = 0; k4 < 16; ++k4) {
        float4 w = wp[k4 * 64 + lane];
        acc2 += rlane(v.x, k4) * w.x + rlane(v.y, k4) * w.y
              + rlane(v.z, k4) * w.z + rlane(v.w, k4) * w.w;
    }
    h2b[(size_t)d * 64 + lane] = f2bf(acc2);
    float ps = acc2 * as2v[lane];
    float pd = acc2 * ad2v[lane];
#pragma unroll
    for (int m = 1; m < 64; m <<= 1) { ps += __shfl_xor(ps, m, 64); pd += __shfl_xor(pd, m, 64); }
    if (lane == 0) { a_s2[d] = ps; a_d2[d] = pd; }
}

// ============ agg2: two-phase LDS-staged, 1 head ============
__global__ __launch_bounds__(256) void agg2(const int* __restrict__ srclist,
                                            const int* __restrict__ offs,
                                            const int* __restrict__ deg,
                                            const float* __restrict__ a_s,
                                            const float* __restrict__ a_d,
                                            const unsigned short* __restrict__ h2b,
                                            const float* __restrict__ b2,
                                            float* __restrict__ out) {
    __shared__ int   sidxL[4][CHUNK];
    __shared__ float exL[4][CHUNK];
    int wv   = threadIdx.x >> 6;
    int lane = threadIdx.x & 63;
    int d    = blockIdx.x * 4 + wv;
    int base = offs[d], dg = deg[d];
    int sub  = lane >> 4, cl = lane & 15;
    float ad    = a_d[d];
    float eself = lrelu(a_s[d] + ad);
    float4 acc = {0.f, 0.f, 0.f, 0.f};
    float  sm  = 0.f;

    for (int c0 = 0; c0 < dg; c0 += CHUNK) {
        int cnt = min(CHUNK, dg - c0);
        // ---- phase 1: 1 lane/edge, 1 exp/lane
        if (lane < cnt) {
            int s = srclist[base + c0 + lane];
            sidxL[wv][lane] = s;
            exL[wv][lane]   = __expf(lrelu(a_s[s] + ad) - eself);
        }
        lds_fence();
        // ---- phase 2
#pragma unroll 4
        for (int k = sub; k < cnt; k += 4) {
            int   s  = sidxL[wv][k];
            float ex = exL[wv][k];
            ushort4 hv = *(const ushort4*)&h2b[(size_t)s * 64 + 4 * cl];
            acc.x += bf2f(hv.x) * ex; acc.y += bf2f(hv.y) * ex;
            acc.z += bf2f(hv.z) * ex; acc.w += bf2f(hv.w) * ex;
            sm += ex;
        }
        __builtin_amdgcn_wave_barrier();
    }
    if (sub == 0) {
        ushort4 hv = *(const ushort4*)&h2b[(size_t)d * 64 + 4 * cl];
        acc.x += bf2f(hv.x); acc.y += bf2f(hv.y);
        acc.z += bf2f(hv.z); acc.w += bf2f(hv.w);
        sm += 1.f;
    }
#pragma unroll
    for (int m = 16; m < 64; m <<= 1) {
        acc.x += __shfl_xor(acc.x, m, 64);
        acc.y += __shfl_xor(acc.y, m, 64);
        acc.z += __shfl_xor(acc.z, m, 64);
        acc.w += __shfl_xor(acc.w, m, 64);
        sm    += __shfl_xor(sm, m, 64);
    }
    if (sub == 0) {
        float inv = 1.f / sm;
        float4 bv = *(const float4*)&b2[4 * cl];
        float4 o;
        o.x = acc.x * inv + bv.x;
        o.y = acc.y * inv + bv.y;
        o.z = acc.z * inv + bv.z;
        o.w = acc.w * inv + bv.w;
        *(float4*)&out[d * 64 + 4 * cl] = o;
    }
}

extern "C" void kernel_launch(void* const* d_in, const int* in_sizes, int n_in,
                              void* d_out, int out_size, void* d_ws, size_t ws_size,
                              hipStream_t stream) {
    const float* x   = (const float*)d_in[0];
    const int*   ei  = (const int*)d_in[1];
    const float* W1  = (const float*)d_in[2];
    const float* as1 = (const float*)d_in[3];
    const float* ad1 = (const float*)d_in[4];
    const float* b1  = (const float*)d_in[5];
    const float* W2  = (const float*)d_in[6];
    const float* as2 = (const float*)d_in[7];
    const float* ad2 = (const float*)d_in[8];
    const float* b2  = (const float*)d_in[9];
    float* out = (float*)d_out;

    float* ws = (float*)d_ws;
    unsigned short* h1b = (unsigned short*)ws;             // 3.2M ushort
    unsigned short* h2b = (unsigned short*)(ws + 1600000); // 3.2M ushort
    float* a_s1 = ws + 3200000;              // 400,000
    float* a_d1 = a_s1 + 400000;             // 400,000
    float* a_s2 = a_d1 + 400000;             // 50,000
    float* a_d2 = a_s2 + 50000;              // 50,000
    int* deg     = (int*)(a_d2 + 50000);     // 50,000
    int* offs    = deg + 50000;              // 50,000
    int* cursor  = offs + 50000;             // 50,000
    int* bsum    = cursor + 50000;           // 256
    int* srclist = bsum + 256;               // 800,000
    float* W1S   = (float*)(srclist + 800000); // 8,192
    float* W2S   = W1S + 8192;               // 4,096

    // ---- CSR build + weight swizzle
    hipMemsetAsync(deg, 0, (size_t)NN * 4, stream);
    hist<<<(NE + 255) / 256, 256, 0, stream>>>(ei, deg);
    prep<<<48, 256, 0, stream>>>(W1, W2, W1S, W2S);
    scan1<<<256, 256, 0, stream>>>(deg, offs, bsum);
    scan2<<<1, 256, 0, stream>>>(bsum);
    scan3<<<(NN + 255) / 256, 256, 0, stream>>>(offs, bsum, cursor);
    scatter<<<(NE + 255) / 256, 256, 0, stream>>>(ei, cursor, srclist);

    // ---- layer 1 GEMM
    gemm1<<<3125, 256, 0, stream>>>(x, W1S, as1, ad1, h1b, a_s1, a_d1);
    // ---- layer 1 aggregate + fused layer 2 GEMM/logits
    agg1<<<12500, 256, 0, stream>>>(srclist, offs, deg, a_s1, a_d1, h1b, b1,
                                    W2S, as2, ad2, h2b, a_s2, a_d2);
    // ---- layer 2 aggregate
    agg2<<<12500, 256, 0, stream>>>(srclist, offs, deg, a_s2, a_d2, h2b, b2, out);
}